// Round 3
// baseline (123.781 us; speedup 1.0000x reference)
//
#include <hip/hip_runtime.h>

// ---------------------------------------------------------------------------
// PolyDecoder via SYMMETRY FOLDING: polyfeats(z) has only 1287 distinct
// monomials (multisets of 8 vars, deg<=5) vs 37449 columns. Fold W's columns
// into buckets (exact f32 sums), then GEMM with K=1312 (41 MFMA steps) --
// 28.6x less matrix work, no partials, no reduce kernel.
//
// Pipeline: setup_lut (k -> bucket rank, 75KB)  ->  fold_w (64 blocks, one
// per out-row: stream 150KB of W, LDS f32-atomic into 1312 buckets, emit
// fragment-layout Wt=168KB)  ->  poly_gemm (256 blocks x 16 rows: build 1287
// features/row in LDS from a constexpr (parent,zdigit) table, 41-step
// f16 MFMA GEMM, direct out write).
//
// Bucket order (shared by LUT rank & feature table): degree-major, within a
// degree lexicographic over ascending tuples d1<=...<=dd. Degree starts:
// buckets {0,1,9,45,165,495}, original k {0,1,9,73,585,4681}.
// Fragment conventions (identical to previous verified kernel):
//   A: row=lane&15, k=(lane>>4)*8+j ; B: col=lane&15, k=(lane>>4)*8+j
//   C/D: col=lane&15, row=(lane>>4)*4+reg
// ---------------------------------------------------------------------------

#define TOTAL_TERMS 37449
#define NBUCKET 1287
#define KPAD 1312            // 41 * 32
#define FSTRIDE 1320         // feats LDS stride in halves: 2640B = 16B-mult,
                             // 660 dw == 20 mod 32 banks -> 2-way (free)
#define LUT_BYTES 76800

typedef _Float16 half8 __attribute__((ext_vector_type(8)));
typedef float f32x4 __attribute__((ext_vector_type(4)));

__device__ __constant__ int KSTART[6] = {0, 1, 9, 73, 585, 4681};
__device__ __constant__ int BSTART[6] = {0, 1, 9, 45, 165, 495};
// NTAB[m][c] = C(m+7-c, m) = #ascending tuples of length m with digits >= c
__device__ __constant__ int NTAB[5][8] = {
    {1, 1, 1, 1, 1, 1, 1, 1},
    {8, 7, 6, 5, 4, 3, 2, 1},
    {36, 28, 21, 15, 10, 6, 3, 1},
    {120, 84, 56, 35, 20, 10, 4, 1},
    {330, 210, 126, 70, 35, 15, 5, 1}};

// k -> bucket: decompose degree+digits (base 8), sort, combinatorial rank.
__global__ __launch_bounds__(256) void setup_lut(unsigned short* __restrict__ lut) {
    int k = blockIdx.x * 256 + threadIdx.x;
    if (k >= TOTAL_TERMS) return;
    int d = 0;
#pragma unroll
    for (int i = 1; i <= 5; ++i)
        if (k >= KSTART[i]) d = i;
    int loc = k - KSTART[d];
    int dg[5] = {0, 0, 0, 0, 0};
    for (int i = d - 1; i >= 0; --i) { dg[i] = loc & 7; loc >>= 3; }
    for (int i = 1; i < d; ++i) {              // insertion sort ascending
        int v = dg[i], j = i;
        while (j > 0 && dg[j - 1] > v) { dg[j] = dg[j - 1]; --j; }
        dg[j] = v;
    }
    int rank = 0, lo = 0;
    for (int i = 0; i < d; ++i) {
        int m = d - 1 - i;
        for (int c = lo; c < dg[i]; ++c) rank += NTAB[m][c];
        lo = dg[i];
    }
    lut[k] = (unsigned short)(BSTART[d] + rank);
}

// One block per output row n: stream W[n][*], fold into LDS buckets, write
// fragment-layout Wt. Frag element (s,h,lane,j) = Wfold[16h+(lane&15)][8t+j]
// with t = 4s + ((lane>>4)&3)  =>  block n (h=n>>4) writes t-th half8 at
// lane = (n&15) + (t&3)*16, s = t>>2.
__global__ __launch_bounds__(1024) void fold_w(const float* __restrict__ W,
                                               const float* __restrict__ bias,
                                               const unsigned short* __restrict__ lut,
                                               _Float16* __restrict__ Wt) {
    __shared__ float bucket[KPAD];
    int tid = threadIdx.x;
    int n = blockIdx.x;                        // 0..63
    for (int i = tid; i < KPAD; i += 1024) bucket[i] = 0.f;
    __syncthreads();
    const float* Wrow = W + (size_t)n * TOTAL_TERMS;
    for (int base = 0; base < TOTAL_TERMS; base += 16384) {
        float v[16];
        int bi[16];
        // batch loads first (deep MLP), then LDS atomics
#pragma unroll
        for (int j = 0; j < 16; ++j) {
            int k = base + tid + j * 1024;
            bool ok = k < TOTAL_TERMS;
            v[j] = ok ? Wrow[k] : 0.f;
            bi[j] = ok ? (int)lut[k] : (KPAD - 1);   // pad bucket (stays ~0)
        }
#pragma unroll
        for (int j = 0; j < 16; ++j)
            if (v[j] != 0.f) atomicAdd(&bucket[bi[j]], v[j]);
    }
    __syncthreads();
    if (tid == 0) bucket[0] += bias[n];        // bias folds into const feature
    __syncthreads();
    if (tid < KPAD / 8) {                      // 164 half8 stores
        int t = tid;
        half8 hv;
#pragma unroll
        for (int j = 0; j < 8; ++j) hv[j] = (_Float16)bucket[8 * t + j];
        int s = t >> 2;
        int lane = (n & 15) + (t & 3) * 16;
        int h = n >> 4;
        *(half8*)(Wt + ((size_t)((s * 4 + h) * 64 + lane)) * 8) = hv;
    }
}

// Compile-time feature-expansion table: entry = parent | zdigit<<11 | dest<<15.
// Enumerates degrees 2..5 over ascending multisets, per-degree padded to a
// multiple of 32 (pads write dump slot 1311, re-zeroed later).
// Padded counts {64,128,352,800} (real {36,120,330,792}), total 1344.
struct ATab {
    unsigned int t[1344];
    constexpr ATab() : t() {
        int last[1287] = {};
        last[0] = 0;
        for (int c = 0; c < 8; ++c) last[1 + c] = c;
        int starts[6] = {0, 1, 9, 45, 165, 495};
        int pcnt[6] = {0, 0, 64, 128, 352, 800};
        int pos = 0;
        for (int d = 2; d <= 5; ++d) {
            int ps = starts[d - 1], pe = starts[d];
            int dest = starts[d];
            int cnt = 0;
            for (int p = ps; p < pe; ++p)
                for (int c = last[p]; c < 8; ++c) {
                    last[dest] = c;
                    t[pos++] = (unsigned)p | ((unsigned)c << 11) |
                               ((unsigned)dest << 15);
                    ++dest; ++cnt;
                }
            for (; cnt < pcnt[d]; ++cnt)
                t[pos++] = 0u | (0u << 11) | (1311u << 15);
        }
    }
};
__device__ const ATab A_TAB{};

// 256 blocks x 16 rows. 8 waves: h = w&3 (16-col group), kh = w>>2 (K half,
// interleaved: wave kh does steps s = 2i+kh). K-halves merged via LDS.
__global__ __launch_bounds__(512) void poly_gemm(const float* __restrict__ z,
                                                 const _Float16* __restrict__ Wt,
                                                 float* __restrict__ out) {
    __shared__ _Float16 feats[16][FSTRIDE];
    __shared__ f32x4 sacc[4][64];
    int tid = threadIdx.x;
    int lane = tid & 63;
    int w = tid >> 6;
    int h = w & 3;
    int kh = w >> 2;
    int mb = blockIdx.x;                       // rows [mb*16, +16)

    // ---- B prologue: prefetch this wave's first 8 steps (s = 2i+kh) ----
    const char* gb = (const char*)Wt + (size_t)(h * 64 + lane) * 16
                   + (size_t)kh * 4096;        // +8192 per i
    half8 Bk[2][8];
#pragma unroll
    for (int i = 0; i < 8; ++i)
        Bk[0][i] = *(const half8*)(gb + (size_t)i * 8192);

    // ---- stage z -> deg0/deg1 features ----
    if (tid < 128) {
        int row = tid >> 3, c = tid & 7;
        float v = z[(size_t)(mb * 16 + row) * 8 + c];
        feats[row][1 + c] = (_Float16)v;
        if (c == 0) feats[row][0] = (_Float16)1.f;
    }

    // ---- feature expansion, degree by degree (parents strictly lower) ----
    int sub = tid & 31, row = tid >> 5;
    const int PS[4] = {0, 64, 192, 544};
    const int PTRIP[4] = {2, 4, 11, 25};
#pragma unroll
    for (int dd = 0; dd < 4; ++dd) {
        __syncthreads();
        int base = PS[dd] + sub;
#pragma unroll
        for (int e = 0; e < PTRIP[dd]; ++e) {
            unsigned v = A_TAB.t[base + (e << 5)];
            int p = v & 2047;
            int c = (v >> 11) & 15;
            int dst = v >> 15;
            feats[row][dst] = feats[row][p] * feats[row][1 + c];
        }
    }
    __syncthreads();
    if (sub < 25) feats[row][1287 + sub] = (_Float16)0.f;  // zero K-pad
    __syncthreads();

    // ---- GEMM: 41 steps split even/odd across kh; 21 (kh=0) / 20 (kh=1) ----
    f32x4 acc0 = {0.f, 0.f, 0.f, 0.f}, acc1 = {0.f, 0.f, 0.f, 0.f};
    int q = (lane >> 4) & 3;
    int arow = lane & 15;
    const _Float16* ap = &feats[arow][kh * 32 + q * 8];  // + i*64 per step

#define STEP(i, bank, slot)                                                    \
    {                                                                          \
        half8 av = *(const half8*)(ap + (i) * 64);                             \
        if ((i) & 1)                                                           \
            acc1 = __builtin_amdgcn_mfma_f32_16x16x32_f16(av, Bk[bank][slot],  \
                                                          acc1, 0, 0, 0);      \
        else                                                                   \
            acc0 = __builtin_amdgcn_mfma_f32_16x16x32_f16(av, Bk[bank][slot],  \
                                                          acc0, 0, 0, 0);      \
    }

    // group 0: compute i=0..7 from Bk[0], prefetch i=8..15 -> Bk[1]
#pragma unroll
    for (int i = 0; i < 8; ++i)
        Bk[1][i] = *(const half8*)(gb + (size_t)(8 + i) * 8192);
#pragma unroll
    for (int i = 0; i < 8; ++i) STEP(i, 0, i)
    // group 1: compute i=8..15 from Bk[1], prefetch i=16..19(+20) -> Bk[0]
#pragma unroll
    for (int i = 0; i < 4; ++i)
        Bk[0][i] = *(const half8*)(gb + (size_t)(16 + i) * 8192);
    if (kh == 0) Bk[0][4] = *(const half8*)(gb + (size_t)20 * 8192);
#pragma unroll
    for (int i = 8; i < 16; ++i) STEP(i, 1, i - 8)
    // tail: i=16..19, plus i=20 for kh==0
#pragma unroll
    for (int i = 16; i < 20; ++i) STEP(i, 0, i - 16)
    if (kh == 0) STEP(20, 0, 4)
#undef STEP

    f32x4 accf = acc0 + acc1;

    // ---- merge K halves, write out ----
    if (kh == 1) sacc[h][lane] = accf;
    __syncthreads();
    if (kh == 0) {
        accf += sacc[h][lane];
        int col = h * 16 + (lane & 15);
        int r0 = mb * 16 + q * 4;
#pragma unroll
        for (int r = 0; r < 4; ++r)
            out[(size_t)(r0 + r) * 64 + col] = accf[r];
    }
}

extern "C" void kernel_launch(void* const* d_in, const int* in_sizes, int n_in,
                              void* d_out, int out_size, void* d_ws, size_t ws_size,
                              hipStream_t stream) {
    (void)in_sizes; (void)n_in; (void)out_size; (void)ws_size;
    const float* z = (const float*)d_in[0];
    const float* W = (const float*)d_in[1];
    const float* b = (const float*)d_in[2];
    float* out = (float*)d_out;

    unsigned short* lut = (unsigned short*)d_ws;
    _Float16* Wt = (_Float16*)((char*)d_ws + LUT_BYTES);   // 41*4096 B = 168KB

    hipLaunchKernelGGL(setup_lut, dim3((TOTAL_TERMS + 255) / 256), dim3(256), 0,
                       stream, lut);
    hipLaunchKernelGGL(fold_w, dim3(64), dim3(1024), 0, stream, W, b, lut, Wt);
    hipLaunchKernelGGL(poly_gemm, dim3(256), dim3(512), 0, stream, z, Wt, out);
}

// Round 5
// 100.178 us; speedup vs baseline: 1.2356x; 1.2356x over previous
//
#include <hip/hip_runtime.h>

// ---------------------------------------------------------------------------
// PolyDecoder via SYMMETRY FOLDING: polyfeats(z) has only 1287 distinct
// monomials (multisets of 8 vars, deg<=5) vs 37449 columns. Fold W's columns
// into buckets (exact f32 sums), then GEMM with K=1312 (41 MFMA steps).
//
// R5: fully device-side, deterministic, atomic-free CSR (R4's pageable-host
// hipMemcpyAsync during graph capture is the suspected container killer).
//   setup_csr: thread per k computes bucket b(k) (R3-verified ranking) AND
//     position-in-bucket = lex multiset-permutation rank r(k) in [0,cnt).
//     Scatter slots[b*120 + r] = k (fixed 120-slot/15-group stride; deg5 max
//     cnt = 120 fits exactly). The r==0 representative writes ngrp[b] =
//     ceil(cnt/8) and the <=7 pad sentinels of the last group. No atomics,
//     no scan, no memset, deterministic.
//   fold_gather: thread per (row n, bucket b): sum its ngrp[b] groups
//     (8-wide gathers from L2) and write ONE f16 at its Wt fragment slot
//     (layout identical to R3's verified fold). XCD swizzle pins each row's
//     6 bucket-chunks to one XCD.
//   poly_gemm: byte-identical to R3's verified kernel.
//
// Bucket order (shared by CSR & feature table): degree-major, within a
// degree lexicographic over ascending tuples d1<=...<=dd. Degree starts:
// buckets {0,1,9,45,165,495}, original k {0,1,9,73,585,4681}.
// Fragment conventions (identical to previous verified kernels):
//   A: row=lane&15, k=(lane>>4)*8+j ; B: col=lane&15, k=(lane>>4)*8+j
//   C/D: col=lane&15, row=(lane>>4)*4+reg
// ---------------------------------------------------------------------------

#define TOTAL_TERMS 37449
#define NBUCKET 1287
#define KPAD 1312            // 41 * 32
#define FSTRIDE 1320         // feats LDS stride in halves
#define SLOTS_PER_B 120      // 15 groups of 8; deg5 max cnt = 120
#define NGRP_OFF 0           // u16[1312]                     (2624 B)
#define SLOTS_OFF 4096       // u16[1287*120]                 (308880 B)
#define WT_OFFSET 315392     // 4096 + 76*4096; Wt = 41*4096 B (167936 B)

typedef _Float16 half8 __attribute__((ext_vector_type(8)));
typedef float f32x4 __attribute__((ext_vector_type(4)));

__device__ __constant__ int KSTART[6] = {0, 1, 9, 73, 585, 4681};
__device__ __constant__ int BSTART[6] = {0, 1, 9, 45, 165, 495};
// NTAB[m][c] = C(m+7-c, m) = #ascending tuples of length m with digits >= c
__device__ __constant__ int NTAB[5][8] = {
    {1, 1, 1, 1, 1, 1, 1, 1},
    {8, 7, 6, 5, 4, 3, 2, 1},
    {36, 28, 21, 15, 10, 6, 3, 1},
    {120, 84, 56, 35, 20, 10, 4, 1},
    {330, 210, 126, 70, 35, 15, 5, 1}};
__device__ __constant__ int FACT[6] = {1, 1, 2, 6, 24, 120};

// ---------------------------------------------------------------------------
// setup_csr: thread per k. Bucket rank = R3-verified math; in-bucket position
// = lexicographic multiset-permutation rank of k's digit string (MSB-first).
// ---------------------------------------------------------------------------
__global__ __launch_bounds__(256) void setup_csr(unsigned short* __restrict__ ngrp,
                                                 unsigned short* __restrict__ slots) {
    int k = blockIdx.x * 256 + threadIdx.x;
    if (k >= TOTAL_TERMS) return;

    int d = 0;
#pragma unroll
    for (int i = 1; i <= 5; ++i)
        if (k >= KSTART[i]) d = i;
    int loc = k - KSTART[d];
    int dgo[5] = {0, 0, 0, 0, 0};              // original order, MSB-first
    for (int i = d - 1; i >= 0; --i) { dgo[i] = loc & 7; loc >>= 3; }

    // ---- bucket: sort ascending, combinatorial rank (R3-verified) ----
    int dg[5];
#pragma unroll
    for (int i = 0; i < 5; ++i) dg[i] = dgo[i];
    for (int i = 1; i < d; ++i) {              // insertion sort ascending
        int v = dg[i], j = i;
        while (j > 0 && dg[j - 1] > v) { dg[j] = dg[j - 1]; --j; }
        dg[j] = v;
    }
    int brank = 0, lo = 0;
    for (int i = 0; i < d; ++i) {
        int m = d - 1 - i;
        for (int c = lo; c < dg[i]; ++c) brank += NTAB[m][c];
        lo = dg[i];
    }
    int b = BSTART[d] + brank;

    // ---- in-bucket position: multiset permutation lex rank of dgo ----
    int mult[8] = {0, 0, 0, 0, 0, 0, 0, 0};
    for (int i = 0; i < d; ++i) mult[dgo[i]]++;
    int D = 1;
#pragma unroll
    for (int c = 0; c < 8; ++c) D *= FACT[mult[c]];
    int cnt = FACT[d] / D;                     // multiset permutation count
    int r = 0;
    for (int i = 0; i < d; ++i) {
        int rem = d - 1 - i;
        for (int c = 0; c < dgo[i]; ++c)
            if (mult[c] > 0) r += FACT[rem] * mult[c] / D;  // exact
        D /= mult[dgo[i]];                     // fact[m]/fact[m-1] = m
        mult[dgo[i]]--;
    }

    slots[b * SLOTS_PER_B + r] = (unsigned short)k;
    if (r == 0) {                              // unique representative
        int ng = (cnt + 7) >> 3;
        ngrp[b] = (unsigned short)ng;
        for (int i = cnt; i < ng * 8; ++i)     // pad last group (<=7 writes)
            slots[b * SLOTS_PER_B + i] = 0xFFFFu;
    }
}

// ---------------------------------------------------------------------------
// fold_gather: grid 384 flat blocks x 256 threads.
// lin&7 = XCD; g = lin>>3 in [0,48): n = xcd*8 + g/6, bucket chunk bx = g%6.
// Thread owns bucket b = bx*256 + tid; sums its padded 8-slot groups.
// ---------------------------------------------------------------------------
__global__ __launch_bounds__(256) void fold_gather(const float* __restrict__ W,
                                                   const float* __restrict__ bias,
                                                   const unsigned short* __restrict__ ngrp,
                                                   const unsigned short* __restrict__ slots,
                                                   _Float16* __restrict__ Wt) {
    int lin = blockIdx.x;              // [0, 384)
    int xcd = lin & 7;
    int g   = lin >> 3;                // [0, 48)
    int n   = xcd * 8 + g / 6;         // [0, 64): row, pinned to one XCD
    int bx  = g % 6;
    int b   = bx * 256 + threadIdx.x;  // [0, 1536)
    if (b >= KPAD) return;

    float s = 0.f;
    if (b < NBUCKET) {
        const float* Wrow = W + (size_t)n * TOTAL_TERMS;
        const unsigned short* sb = slots + (size_t)b * SLOTS_PER_B;
        int ng = ngrp[b];
        for (int gg = 0; gg < ng; ++gg) {
            uint4 sv = *(const uint4*)(sb + (size_t)gg * 8);  // 8 x u16, 16B-al
            unsigned k0 = sv.x & 0xFFFFu, k1 = sv.x >> 16;
            unsigned k2 = sv.y & 0xFFFFu, k3 = sv.y >> 16;
            unsigned k4 = sv.z & 0xFFFFu, k5 = sv.z >> 16;
            unsigned k6 = sv.w & 0xFFFFu, k7 = sv.w >> 16;
            float v0 = (k0 != 0xFFFFu) ? Wrow[k0] : 0.f;
            float v1 = (k1 != 0xFFFFu) ? Wrow[k1] : 0.f;
            float v2 = (k2 != 0xFFFFu) ? Wrow[k2] : 0.f;
            float v3 = (k3 != 0xFFFFu) ? Wrow[k3] : 0.f;
            float v4 = (k4 != 0xFFFFu) ? Wrow[k4] : 0.f;
            float v5 = (k5 != 0xFFFFu) ? Wrow[k5] : 0.f;
            float v6 = (k6 != 0xFFFFu) ? Wrow[k6] : 0.f;
            float v7 = (k7 != 0xFFFFu) ? Wrow[k7] : 0.f;
            s += ((v0 + v1) + (v2 + v3)) + ((v4 + v5) + (v6 + v7));
        }
        if (b == 0) s += bias[n];      // bias folds into const feature
    }
    // write folded element (col n, k b) at its fragment position
    // (identical layout to R3's verified fold_w store)
    int ss = b >> 5, kk = b & 31, quad = kk >> 3, j = kk & 7;
    int lane = (n & 15) + quad * 16;
    Wt[((size_t)((ss * 4 + (n >> 4)) * 64 + lane)) * 8 + j] = (_Float16)s;
}

// ---------------------------------------------------------------------------
// Compile-time feature-expansion table: entry = parent | zdigit<<11 | dest<<15.
// Enumerates degrees 2..5 over ascending multisets, per-degree padded to a
// multiple of 32 (pads write dump slot 1311, re-zeroed later).
// Padded counts {64,128,352,800} (real {36,120,330,792}), total 1344.
// ---------------------------------------------------------------------------
struct ATab {
    unsigned int t[1344];
    constexpr ATab() : t() {
        int last[1287] = {};
        last[0] = 0;
        for (int c = 0; c < 8; ++c) last[1 + c] = c;
        int starts[6] = {0, 1, 9, 45, 165, 495};
        int pcnt[6] = {0, 0, 64, 128, 352, 800};
        int pos = 0;
        for (int d = 2; d <= 5; ++d) {
            int ps = starts[d - 1], pe = starts[d];
            int dest = starts[d];
            int cnt = 0;
            for (int p = ps; p < pe; ++p)
                for (int c = last[p]; c < 8; ++c) {
                    last[dest] = c;
                    t[pos++] = (unsigned)p | ((unsigned)c << 11) |
                               ((unsigned)dest << 15);
                    ++dest; ++cnt;
                }
            for (; cnt < pcnt[d]; ++cnt)
                t[pos++] = 0u | (0u << 11) | (1311u << 15);
        }
    }
};
__device__ const ATab A_TAB{};

// 256 blocks x 16 rows. 8 waves: h = w&3 (16-col group), kh = w>>2 (K half,
// interleaved: wave kh does steps s = 2i+kh). K-halves merged via LDS.
__global__ __launch_bounds__(512) void poly_gemm(const float* __restrict__ z,
                                                 const _Float16* __restrict__ Wt,
                                                 float* __restrict__ out) {
    __shared__ _Float16 feats[16][FSTRIDE];
    __shared__ f32x4 sacc[4][64];
    int tid = threadIdx.x;
    int lane = tid & 63;
    int w = tid >> 6;
    int h = w & 3;
    int kh = w >> 2;
    int mb = blockIdx.x;                       // rows [mb*16, +16)

    // ---- B prologue: prefetch this wave's first 8 steps (s = 2i+kh) ----
    const char* gb = (const char*)Wt + (size_t)(h * 64 + lane) * 16
                   + (size_t)kh * 4096;        // +8192 per i
    half8 Bk[2][8];
#pragma unroll
    for (int i = 0; i < 8; ++i)
        Bk[0][i] = *(const half8*)(gb + (size_t)i * 8192);

    // ---- stage z -> deg0/deg1 features ----
    if (tid < 128) {
        int row = tid >> 3, c = tid & 7;
        float v = z[(size_t)(mb * 16 + row) * 8 + c];
        feats[row][1 + c] = (_Float16)v;
        if (c == 0) feats[row][0] = (_Float16)1.f;
    }

    // ---- feature expansion, degree by degree (parents strictly lower) ----
    int sub = tid & 31, row = tid >> 5;
    const int PS[4] = {0, 64, 192, 544};
    const int PTRIP[4] = {2, 4, 11, 25};
#pragma unroll
    for (int dd = 0; dd < 4; ++dd) {
        __syncthreads();
        int base = PS[dd] + sub;
#pragma unroll
        for (int e = 0; e < PTRIP[dd]; ++e) {
            unsigned v = A_TAB.t[base + (e << 5)];
            int p = v & 2047;
            int c = (v >> 11) & 15;
            int dst = v >> 15;
            feats[row][dst] = feats[row][p] * feats[row][1 + c];
        }
    }
    __syncthreads();
    if (sub < 25) feats[row][1287 + sub] = (_Float16)0.f;  // zero K-pad
    __syncthreads();

    // ---- GEMM: 41 steps split even/odd across kh; 21 (kh=0) / 20 (kh=1) ----
    f32x4 acc0 = {0.f, 0.f, 0.f, 0.f}, acc1 = {0.f, 0.f, 0.f, 0.f};
    int q = (lane >> 4) & 3;
    int arow = lane & 15;
    const _Float16* ap = &feats[arow][kh * 32 + q * 8];  // + i*64 per step

#define STEP(i, bank, slot)                                                    \
    {                                                                          \
        half8 av = *(const half8*)(ap + (i) * 64);                             \
        if ((i) & 1)                                                           \
            acc1 = __builtin_amdgcn_mfma_f32_16x16x32_f16(av, Bk[bank][slot],  \
                                                          acc1, 0, 0, 0);      \
        else                                                                   \
            acc0 = __builtin_amdgcn_mfma_f32_16x16x32_f16(av, Bk[bank][slot],  \
                                                          acc0, 0, 0, 0);      \
    }

    // group 0: compute i=0..7 from Bk[0], prefetch i=8..15 -> Bk[1]
#pragma unroll
    for (int i = 0; i < 8; ++i)
        Bk[1][i] = *(const half8*)(gb + (size_t)(8 + i) * 8192);
#pragma unroll
    for (int i = 0; i < 8; ++i) STEP(i, 0, i)
    // group 1: compute i=8..15 from Bk[1], prefetch i=16..19(+20) -> Bk[0]
#pragma unroll
    for (int i = 0; i < 4; ++i)
        Bk[0][i] = *(const half8*)(gb + (size_t)(16 + i) * 8192);
    if (kh == 0) Bk[0][4] = *(const half8*)(gb + (size_t)20 * 8192);
#pragma unroll
    for (int i = 8; i < 16; ++i) STEP(i, 1, i - 8)
    // tail: i=16..19, plus i=20 for kh==0
#pragma unroll
    for (int i = 16; i < 20; ++i) STEP(i, 0, i - 16)
    if (kh == 0) STEP(20, 0, 4)
#undef STEP

    f32x4 accf = acc0 + acc1;

    // ---- merge K halves, write out ----
    if (kh == 1) sacc[h][lane] = accf;
    __syncthreads();
    if (kh == 0) {
        accf += sacc[h][lane];
        int col = h * 16 + (lane & 15);
        int r0 = mb * 16 + q * 4;
#pragma unroll
        for (int r = 0; r < 4; ++r)
            out[(size_t)(r0 + r) * 64 + col] = accf[r];
    }
}

extern "C" void kernel_launch(void* const* d_in, const int* in_sizes, int n_in,
                              void* d_out, int out_size, void* d_ws, size_t ws_size,
                              hipStream_t stream) {
    (void)in_sizes; (void)n_in; (void)out_size; (void)ws_size;
    const float* z = (const float*)d_in[0];
    const float* W = (const float*)d_in[1];
    const float* b = (const float*)d_in[2];
    float* out = (float*)d_out;

    unsigned short* ngrp  = (unsigned short*)((char*)d_ws + NGRP_OFF);
    unsigned short* slots = (unsigned short*)((char*)d_ws + SLOTS_OFF);
    _Float16* Wt = (_Float16*)((char*)d_ws + WT_OFFSET);   // 41*4096 B

    hipLaunchKernelGGL(setup_csr, dim3((TOTAL_TERMS + 255) / 256), dim3(256), 0,
                       stream, ngrp, slots);
    hipLaunchKernelGGL(fold_gather, dim3(384), dim3(256), 0, stream,
                       W, b, ngrp, slots, Wt);
    hipLaunchKernelGGL(poly_gemm, dim3(256), dim3(512), 0, stream, z, Wt, out);
}